// Round 9
// baseline (117.908 us; speedup 1.0000x reference)
//
#include <hip/hip_runtime.h>
#include <math.h>

#define DD 64

typedef __attribute__((ext_vector_type(8))) short bf16x8;
typedef __attribute__((ext_vector_type(4))) float f32x4;

__device__ __forceinline__ unsigned short f2bf(float x) {
    unsigned int u = __float_as_uint(x);
    u += 0x7fffu + ((u >> 16) & 1u);      // round-to-nearest-even
    return (unsigned short)(u >> 16);
}
__device__ __forceinline__ float bflo(unsigned int u) { return __uint_as_float(u << 16); }
__device__ __forceinline__ float bfhi(unsigned int u) { return __uint_as_float(u & 0xffff0000u); }

// ---------------------------------------------------------------------------
// Fused: blocks [0,GB): MFMA GEMM (Xp_bf, s_src, s_dst).
//        blocks [GB, GB+512): multisplit coarse histograms.
// ---------------------------------------------------------------------------
#define GEMM_BLOCKS 196

__global__ __launch_bounds__(256) void k_gemm_count(
    const float* __restrict__ X, const float* __restrict__ W,
    const float* __restrict__ bias, const float* __restrict__ a_src,
    const float* __restrict__ a_dst, unsigned short* __restrict__ Xp_bf,
    float* __restrict__ s_src, float* __restrict__ s_dst,
    const int* __restrict__ e_dst, const int* __restrict__ inc_e,
    const int* __restrict__ inc_v, int* __restrict__ hist_g,
    int* __restrict__ hist_ie, int* __restrict__ hist_iv,
    int N, int E, int P, int M)
{
    if (blockIdx.x >= GEMM_BLOCKS) {
        // ---------------- histogram branch ----------------
        __shared__ int cnt[128];
        int b = blockIdx.x - GEMM_BLOCKS;
        const int* key; int n, B, SH, nblk, blk; int* hist;
        if (b < 256)      { key = e_dst; n = E; B = (N + 511) >> 9; SH = 9; nblk = 256; blk = b;       hist = hist_g;  }
        else if (b < 384) { key = inc_e; n = P; B = (M + 255) >> 8; SH = 8; nblk = 128; blk = b - 256; hist = hist_ie; }
        else              { key = inc_v; n = P; B = (N + 511) >> 9; SH = 9; nblk = 128; blk = b - 384; hist = hist_iv; }
        for (int i = threadIdx.x; i < B; i += 256) cnt[i] = 0;
        __syncthreads();
        int chunk = (n + nblk - 1) / nblk;
        int s = blk * chunk, e = min(n, s + chunk);
        for (int i = s + threadIdx.x; i < e; i += 256)
            atomicAdd(&cnt[key[i] >> SH], 1);
        __syncthreads();
        for (int i = threadIdx.x; i < B; i += 256)
            hist[i * nblk + blk] = cnt[i];
        return;
    }
    // ---------------- GEMM branch ----------------
    int t = threadIdx.x;
    int lane = t & 63;
    int col = lane & 15;
    int kq  = lane >> 4;
    int rowbase = kq * 4;

    bf16x8 bfrag[4][2];
    float bj[4], asr[4], adr[4];
    #pragma unroll
    for (int jt = 0; jt < 4; ++jt) {
        int j = jt * 16 + col;
        #pragma unroll
        for (int ks = 0; ks < 2; ++ks) {
            const float* wp = W + j * DD + ks * 32 + kq * 8;
            float4 w0 = *(const float4*)wp;
            float4 w1 = *(const float4*)(wp + 4);
            bf16x8 bb;
            bb[0] = (short)f2bf(w0.x); bb[1] = (short)f2bf(w0.y);
            bb[2] = (short)f2bf(w0.z); bb[3] = (short)f2bf(w0.w);
            bb[4] = (short)f2bf(w1.x); bb[5] = (short)f2bf(w1.y);
            bb[6] = (short)f2bf(w1.z); bb[7] = (short)f2bf(w1.w);
            bfrag[jt][ks] = bb;
        }
        bj[jt]  = bias[j];
        asr[jt] = a_src[j];
        adr[jt] = a_dst[j];
    }

    int wave  = (blockIdx.x * 256 + t) >> 6;
    int nwave = (GEMM_BLOCKS * 256) >> 6;
    int ntiles = (N + 15) >> 4;
    for (int tile = wave; tile < ntiles; tile += nwave) {
        int r0 = tile * 16;
        int rl = r0 + col;
        if (rl >= N) rl = N - 1;
        const float* xp = X + (size_t)rl * DD + kq * 8;
        float4 x0 = *(const float4*)xp;
        float4 x1 = *(const float4*)(xp + 4);
        float4 x2 = *(const float4*)(xp + 32);
        float4 x3 = *(const float4*)(xp + 36);
        bf16x8 a0, a1;
        a0[0] = (short)f2bf(x0.x); a0[1] = (short)f2bf(x0.y);
        a0[2] = (short)f2bf(x0.z); a0[3] = (short)f2bf(x0.w);
        a0[4] = (short)f2bf(x1.x); a0[5] = (short)f2bf(x1.y);
        a0[6] = (short)f2bf(x1.z); a0[7] = (short)f2bf(x1.w);
        a1[0] = (short)f2bf(x2.x); a1[1] = (short)f2bf(x2.y);
        a1[2] = (short)f2bf(x2.z); a1[3] = (short)f2bf(x2.w);
        a1[4] = (short)f2bf(x3.x); a1[5] = (short)f2bf(x3.y);
        a1[6] = (short)f2bf(x3.z); a1[7] = (short)f2bf(x3.w);

        f32x4 acc[4];
        #pragma unroll
        for (int jt = 0; jt < 4; ++jt) {
            f32x4 c = {bj[jt], bj[jt], bj[jt], bj[jt]};
            c = __builtin_amdgcn_mfma_f32_16x16x32_bf16(a0, bfrag[jt][0], c, 0, 0, 0);
            c = __builtin_amdgcn_mfma_f32_16x16x32_bf16(a1, bfrag[jt][1], c, 0, 0, 0);
            acc[jt] = c;
        }

        int orow = r0 + rowbase;
        #pragma unroll
        for (int jt = 0; jt < 4; ++jt) {
            #pragma unroll
            for (int r = 0; r < 4; ++r) {
                int rr = orow + r;
                if (rr < N)
                    Xp_bf[(size_t)rr * DD + jt * 16 + col] = f2bf(acc[jt][r]);
            }
        }

        float vs[4], vd[4];
        #pragma unroll
        for (int r = 0; r < 4; ++r) {
            vs[r] = acc[0][r] * asr[0] + acc[1][r] * asr[1]
                  + acc[2][r] * asr[2] + acc[3][r] * asr[3];
            vd[r] = acc[0][r] * adr[0] + acc[1][r] * adr[1]
                  + acc[2][r] * adr[2] + acc[3][r] * adr[3];
        }
        #pragma unroll
        for (int off = 1; off < 16; off <<= 1) {
            #pragma unroll
            for (int r = 0; r < 4; ++r) {
                vs[r] += __shfl_xor(vs[r], off, 64);
                vd[r] += __shfl_xor(vd[r], off, 64);
            }
        }
        if (col == 0) {
            #pragma unroll
            for (int r = 0; r < 4; ++r) {
                int rr = orow + r;
                if (rr < N) { s_src[rr] = vs[r]; s_dst[rr] = vd[r]; }
            }
        }
    }
}

// ---------------------------------------------------------------------------
// In-place exclusive scan (one block, 1024 threads, 4 elems/thread).
// ---------------------------------------------------------------------------
__device__ void block_scan4(int* a, int len)
{
    __shared__ int wtot[16];
    __shared__ int carry_s;
    int tid = threadIdx.x, lane = tid & 63, wid = tid >> 6;
    if (tid == 0) carry_s = 0;
    __syncthreads();
    for (int base = 0; base < len; base += 4096) {
        int i0 = base + tid * 4;
        int v[4];
        #pragma unroll
        for (int k = 0; k < 4; ++k) { int i = i0 + k; v[k] = (i < len) ? a[i] : 0; }
        int s = v[0] + v[1] + v[2] + v[3];
        int incl = s;
        #pragma unroll
        for (int off = 1; off < 64; off <<= 1) {
            int t = __shfl_up(incl, off, 64);
            if (lane >= off) incl += t;
        }
        if (lane == 63) wtot[wid] = incl;
        __syncthreads();
        int carry = carry_s;
        int woff = 0;
        for (int wj = 0; wj < wid; ++wj) woff += wtot[wj];
        int excl = carry + woff + incl - s;
        int run = excl;
        #pragma unroll
        for (int k = 0; k < 4; ++k) { int i = i0 + k; if (i < len) a[i] = run; run += v[k]; }
        __syncthreads();
        if (tid == 1023) carry_s = run;
        __syncthreads();
    }
    if (tid == 0) a[len] = carry_s;
}

__global__ __launch_bounds__(1024) void k_scan3(
    int* h0, int l0, int* h1, int l1, int* h2, int l2)
{
    if (blockIdx.x == 0)      block_scan4(h0, l0);
    else if (blockIdx.x == 1) block_scan4(h1, l1);
    else                      block_scan4(h2, l2);
}

// ---------------------------------------------------------------------------
// Multisplit pass 2: scatter PACKED (fine_key | payload<<SH) into
// per-(block,bucket) regions. 4 B per item.
// ---------------------------------------------------------------------------
__global__ __launch_bounds__(256) void k_scat(
    const int* __restrict__ e_dst, const int* __restrict__ e_src,
    const int* __restrict__ inc_e, const int* __restrict__ inc_v,
    const int* __restrict__ hist_g, const int* __restrict__ hist_ie,
    const int* __restrict__ hist_iv,
    unsigned int* __restrict__ pg, unsigned int* __restrict__ pie,
    unsigned int* __restrict__ piv,
    int E, int P, int N, int M)
{
    __shared__ int cur[128];
    int b = blockIdx.x;
    const int *key, *pay, *base; unsigned int* out;
    int n, B, SH, nblk, blk;
    if (b < 256)      { key = e_dst; pay = e_src; n = E; B = (N + 511) >> 9; SH = 9; nblk = 256; blk = b;       base = hist_g;  out = pg;  }
    else if (b < 384) { key = inc_e; pay = inc_v; n = P; B = (M + 255) >> 8; SH = 8; nblk = 128; blk = b - 256; base = hist_ie; out = pie; }
    else              { key = inc_v; pay = inc_e; n = P; B = (N + 511) >> 9; SH = 9; nblk = 128; blk = b - 384; base = hist_iv; out = piv; }
    for (int i = threadIdx.x; i < B; i += 256) cur[i] = base[i * nblk + blk];
    __syncthreads();
    int chunk = (n + nblk - 1) / nblk;
    int s = blk * chunk, e = min(n, s + chunk);
    int mask = (1 << SH) - 1;
    for (int i = s + threadIdx.x; i < e; i += 256) {
        int k = key[i];
        int pos = atomicAdd(&cur[k >> SH], 1);
        out[pos] = (unsigned int)(k & mask) | ((unsigned int)pay[i] << SH);
    }
}

// ---------------------------------------------------------------------------
// Multisplit pass 3: per-bucket fine counting sort in LDS (packed input).
// ---------------------------------------------------------------------------
__global__ __launch_bounds__(256) void k_fine(
    const int* __restrict__ hist_g, const int* __restrict__ hist_ie,
    const int* __restrict__ hist_iv,
    const unsigned int* __restrict__ pg, const unsigned int* __restrict__ pie,
    const unsigned int* __restrict__ piv,
    int* __restrict__ src_sorted, int* __restrict__ v_sorted,
    int* __restrict__ e_sorted,
    int* __restrict__ start_g, int* __restrict__ start_e,
    int* __restrict__ start_v,
    float* __restrict__ dein, float* __restrict__ dvis, int N, int M)
{
    __shared__ int lh[513];
    __shared__ int lc[512];
    __shared__ int lwt[4];
    __shared__ int lout[10240];
    int Bg = (N + 511) >> 9, Bie = (M + 255) >> 8;
    int b = blockIdx.x, tid = threadIdx.x;
    const int* base; const unsigned int* pr; int* outp; int* startp; float* inv;
    int K, nblk, b0, NK, mode;
    if (b < Bg)            { base = hist_g;  pr = pg;  outp = src_sorted; startp = start_g; inv = nullptr; K = 512; nblk = 256; b0 = b;            NK = N; mode = 0; }
    else if (b < Bg + Bie) { base = hist_ie; pr = pie; outp = v_sorted;   startp = start_e; inv = dein;    K = 256; nblk = 128; b0 = b - Bg;       NK = M; mode = 2; }
    else                   { base = hist_iv; pr = piv; outp = e_sorted;   startp = start_v; inv = dvis;    K = 512; nblk = 128; b0 = b - Bg - Bie; NK = N; mode = 1; }
    int SHF = (K == 512) ? 9 : 8;

    int pbase = base[b0 * nblk], pend = base[(b0 + 1) * nblk];
    int cnt = pend - pbase;
    for (int i = tid; i < K; i += 256) { lh[i] = 0; lc[i] = 0; }
    __syncthreads();
    for (int i = tid; i < cnt; i += 256)
        atomicAdd(&lh[pr[pbase + i] & (K - 1)], 1);
    __syncthreads();

    int per = K >> 8;
    int i0 = tid * per;
    int a0 = lh[i0], a1 = (per == 2) ? lh[i0 + 1] : 0;
    int ssum = a0 + a1;
    int lane = tid & 63, wid = tid >> 6;
    int incl = ssum;
    #pragma unroll
    for (int off = 1; off < 64; off <<= 1) {
        int t = __shfl_up(incl, off, 64);
        if (lane >= off) incl += t;
    }
    if (lane == 63) lwt[wid] = incl;
    __syncthreads();
    int woff = 0;
    for (int wj = 0; wj < wid; ++wj) woff += lwt[wj];
    int excl = woff + incl - ssum;
    lh[i0] = excl;
    if (per == 2) lh[i0 + 1] = excl + a0;
    if (tid == 255) lh[K] = excl + ssum;
    __syncthreads();

    for (int i = tid; i < cnt; i += 256) {
        unsigned int q = pr[pbase + i];
        int kl = q & (K - 1);
        int pos = lh[kl] + atomicAdd(&lc[kl], 1);
        lout[pos < 10240 ? pos : 10239] = (int)(q >> SHF);
    }
    __syncthreads();
    for (int i = tid; i < cnt; i += 256)
        outp[pbase + i] = lout[i];
    for (int k = tid; k < K; k += 256) {
        int node = b0 * K + k;
        if (node < NK) {
            startp[node] = pbase + lh[k];
            if (mode) {
                int d = lh[k + 1] - lh[k];
                inv[node] = d > 0 ? (mode == 1 ? rsqrtf((float)d) : 1.0f / (float)d) : 0.0f;
            }
        }
    }
    int Bj = (NK + K - 1) / K;
    if (tid == 0 && b0 == Bj - 1) startp[NK] = pend;
}

// ---------------------------------------------------------------------------
// He_bf[e][:] = bf16( dein[e] * sum_v Xp[v][:]*dvis[v] ).
// Wave per hyperedge. Member batch staged lane-parallel into per-wave LDS;
// gather loop reads (v, dv) from LDS (no shfl), 2 rows in flight.
// ---------------------------------------------------------------------------
__global__ __launch_bounds__(256, 4) void k_he(
    const int* __restrict__ start_e, const int* __restrict__ v_sorted,
    const unsigned short* __restrict__ Xp_bf, const float* __restrict__ dvis,
    const float* __restrict__ dein, unsigned short* __restrict__ He_bf, int M)
{
    __shared__ int   s_v[4][64];
    __shared__ float s_d[4][64];
    int lane = threadIdx.x & 63, grp = lane >> 3, gl = lane & 7;
    int wv = threadIdx.x >> 6;
    int e = (blockIdx.x * 256 + threadIdx.x) >> 6;
    if (e >= M) return;
    int s = start_e[e], t = start_e[e + 1];
    float a[8] = {0.f, 0.f, 0.f, 0.f, 0.f, 0.f, 0.f, 0.f};
    for (int base = s; base < t; base += 64) {
        int cnt = min(64, t - base);          // wave-uniform
        int v = 0; float dv = 0.f;
        if (lane < cnt) { v = v_sorted[base + lane]; dv = dvis[v]; }
        s_v[wv][lane] = v;
        s_d[wv][lane] = dv;
        int nIter = (cnt + 7) >> 3;           // wave-uniform
        int k = 0;
        for (; k + 1 < nIter; k += 2) {
            int i0 = grp + 8 * k, i1 = i0 + 8;
            int v0 = s_v[wv][i0];      int v1 = s_v[wv][i1];
            float d0 = s_d[wv][i0];    float d1 = s_d[wv][i1];
            uint4 r0 = *(const uint4*)(Xp_bf + (size_t)v0 * DD + gl * 8);
            uint4 r1 = *(const uint4*)(Xp_bf + (size_t)v1 * DD + gl * 8);
            a[0] = fmaf(d0, bflo(r0.x), a[0]); a[1] = fmaf(d0, bfhi(r0.x), a[1]);
            a[2] = fmaf(d0, bflo(r0.y), a[2]); a[3] = fmaf(d0, bfhi(r0.y), a[3]);
            a[4] = fmaf(d0, bflo(r0.z), a[4]); a[5] = fmaf(d0, bfhi(r0.z), a[5]);
            a[6] = fmaf(d0, bflo(r0.w), a[6]); a[7] = fmaf(d0, bfhi(r0.w), a[7]);
            a[0] = fmaf(d1, bflo(r1.x), a[0]); a[1] = fmaf(d1, bfhi(r1.x), a[1]);
            a[2] = fmaf(d1, bflo(r1.y), a[2]); a[3] = fmaf(d1, bfhi(r1.y), a[3]);
            a[4] = fmaf(d1, bflo(r1.z), a[4]); a[5] = fmaf(d1, bfhi(r1.z), a[5]);
            a[6] = fmaf(d1, bflo(r1.w), a[6]); a[7] = fmaf(d1, bfhi(r1.w), a[7]);
        }
        if (k < nIter) {                      // wave-uniform tail
            int i0 = grp + 8 * k;
            int v0 = s_v[wv][i0];
            float d0 = s_d[wv][i0];
            uint4 r0 = *(const uint4*)(Xp_bf + (size_t)v0 * DD + gl * 8);
            a[0] = fmaf(d0, bflo(r0.x), a[0]); a[1] = fmaf(d0, bfhi(r0.x), a[1]);
            a[2] = fmaf(d0, bflo(r0.y), a[2]); a[3] = fmaf(d0, bfhi(r0.y), a[3]);
            a[4] = fmaf(d0, bflo(r0.z), a[4]); a[5] = fmaf(d0, bfhi(r0.z), a[5]);
            a[6] = fmaf(d0, bflo(r0.w), a[6]); a[7] = fmaf(d0, bfhi(r0.w), a[7]);
        }
    }
    #pragma unroll
    for (int off = 8; off < 64; off <<= 1) {
        #pragma unroll
        for (int j = 0; j < 8; ++j) a[j] += __shfl_xor(a[j], off, 64);
    }
    if (grp == 0) {
        float din = dein[e];
        uint4 o;
        o.x = (unsigned)f2bf(a[0] * din) | ((unsigned)f2bf(a[1] * din) << 16);
        o.y = (unsigned)f2bf(a[2] * din) | ((unsigned)f2bf(a[3] * din) << 16);
        o.z = (unsigned)f2bf(a[4] * din) | ((unsigned)f2bf(a[5] * din) << 16);
        o.w = (unsigned)f2bf(a[6] * din) | ((unsigned)f2bf(a[7] * din) << 16);
        *(uint4*)(He_bf + (size_t)e * DD + gl * 8) = o;
    }
}

// ---------------------------------------------------------------------------
// Per-node fused epilogue. Adjacency batch staged lane-parallel into LDS
// (coalesced index load + lane-parallel exp); gather loops read (idx, w)
// from per-wave LDS (no shfl). Invalid lanes carry w=0 / hw=0.
// ---------------------------------------------------------------------------
__global__ __launch_bounds__(256, 4) void k_out(
    const int* __restrict__ start_g, const int* __restrict__ src_sorted,
    const int* __restrict__ start_v, const int* __restrict__ e_sorted,
    const float* __restrict__ ssrc, const float* __restrict__ sdst,
    const unsigned short* __restrict__ Xp_bf, const unsigned short* __restrict__ He_bf,
    const float* __restrict__ dvis, float* __restrict__ out, int N)
{
    __shared__ int   s_i[4][64];
    __shared__ float s_w[4][64];
    int lane = threadIdx.x & 63, grp = lane >> 3, gl = lane & 7;
    int wv = threadIdx.x >> 6;
    int n = (blockIdx.x * 256 + threadIdx.x) >> 6;
    if (n >= N) return;

    float sd = sdst[n];
    int gs = start_g[n], ge = start_g[n + 1];
    float g[8] = {0.f, 0.f, 0.f, 0.f, 0.f, 0.f, 0.f, 0.f};
    float wsum = 0.f;
    for (int base = gs; base < ge; base += 64) {
        int cnt = min(64, ge - base);         // wave-uniform
        int idx = 0; float w = 0.f;
        if (lane < cnt) {
            idx = src_sorted[base + lane];
            float sc = ssrc[idx] + sd;
            sc = sc > 0.f ? sc : 0.2f * sc;
            w = __expf(sc);
        }
        s_i[wv][lane] = idx;
        s_w[wv][lane] = w;
        wsum += w;
        int nIter = (cnt + 7) >> 3;           // wave-uniform
        int k = 0;
        for (; k + 1 < nIter; k += 2) {
            int i0 = grp + 8 * k, i1 = i0 + 8;
            int s0 = s_i[wv][i0];     int s1 = s_i[wv][i1];
            float w0 = s_w[wv][i0];   float w1 = s_w[wv][i1];
            uint4 r0 = *(const uint4*)(Xp_bf + (size_t)s0 * DD + gl * 8);
            uint4 r1 = *(const uint4*)(Xp_bf + (size_t)s1 * DD + gl * 8);
            g[0] = fmaf(w0, bflo(r0.x), g[0]); g[1] = fmaf(w0, bfhi(r0.x), g[1]);
            g[2] = fmaf(w0, bflo(r0.y), g[2]); g[3] = fmaf(w0, bfhi(r0.y), g[3]);
            g[4] = fmaf(w0, bflo(r0.z), g[4]); g[5] = fmaf(w0, bfhi(r0.z), g[5]);
            g[6] = fmaf(w0, bflo(r0.w), g[6]); g[7] = fmaf(w0, bfhi(r0.w), g[7]);
            g[0] = fmaf(w1, bflo(r1.x), g[0]); g[1] = fmaf(w1, bfhi(r1.x), g[1]);
            g[2] = fmaf(w1, bflo(r1.y), g[2]); g[3] = fmaf(w1, bfhi(r1.y), g[3]);
            g[4] = fmaf(w1, bflo(r1.z), g[4]); g[5] = fmaf(w1, bfhi(r1.z), g[5]);
            g[6] = fmaf(w1, bflo(r1.w), g[6]); g[7] = fmaf(w1, bfhi(r1.w), g[7]);
        }
        if (k < nIter) {                      // wave-uniform tail
            int i0 = grp + 8 * k;
            int s0 = s_i[wv][i0];
            float w0 = s_w[wv][i0];
            uint4 r0 = *(const uint4*)(Xp_bf + (size_t)s0 * DD + gl * 8);
            g[0] = fmaf(w0, bflo(r0.x), g[0]); g[1] = fmaf(w0, bfhi(r0.x), g[1]);
            g[2] = fmaf(w0, bflo(r0.y), g[2]); g[3] = fmaf(w0, bfhi(r0.y), g[3]);
            g[4] = fmaf(w0, bflo(r0.z), g[4]); g[5] = fmaf(w0, bfhi(r0.z), g[5]);
            g[6] = fmaf(w0, bflo(r0.w), g[6]); g[7] = fmaf(w0, bfhi(r0.w), g[7]);
        }
    }

    int vs = start_v[n], ve = start_v[n + 1];
    float h[8] = {0.f, 0.f, 0.f, 0.f, 0.f, 0.f, 0.f, 0.f};
    for (int base = vs; base < ve; base += 64) {
        int cnt = min(64, ve - base);         // wave-uniform
        int eidx = 0; float hw = 0.f;
        if (lane < cnt) { eidx = e_sorted[base + lane]; hw = 1.f; }
        s_i[wv][lane] = eidx;
        s_w[wv][lane] = hw;
        int nIter = (cnt + 7) >> 3;           // wave-uniform
        int k = 0;
        for (; k + 1 < nIter; k += 2) {
            int i0 = grp + 8 * k, i1 = i0 + 8;
            int e0 = s_i[wv][i0];     int e1 = s_i[wv][i1];
            float m0 = s_w[wv][i0];   float m1 = s_w[wv][i1];
            uint4 r0 = *(const uint4*)(He_bf + (size_t)e0 * DD + gl * 8);
            uint4 r1 = *(const uint4*)(He_bf + (size_t)e1 * DD + gl * 8);
            h[0] = fmaf(m0, bflo(r0.x), h[0]); h[1] = fmaf(m0, bfhi(r0.x), h[1]);
            h[2] = fmaf(m0, bflo(r0.y), h[2]); h[3] = fmaf(m0, bfhi(r0.y), h[3]);
            h[4] = fmaf(m0, bflo(r0.z), h[4]); h[5] = fmaf(m0, bfhi(r0.z), h[5]);
            h[6] = fmaf(m0, bflo(r0.w), h[6]); h[7] = fmaf(m0, bfhi(r0.w), h[7]);
            h[0] = fmaf(m1, bflo(r1.x), h[0]); h[1] = fmaf(m1, bfhi(r1.x), h[1]);
            h[2] = fmaf(m1, bflo(r1.y), h[2]); h[3] = fmaf(m1, bfhi(r1.y), h[3]);
            h[4] = fmaf(m1, bflo(r1.z), h[4]); h[5] = fmaf(m1, bfhi(r1.z), h[5]);
            h[6] = fmaf(m1, bflo(r1.w), h[6]); h[7] = fmaf(m1, bfhi(r1.w), h[7]);
        }
        if (k < nIter) {                      // wave-uniform tail
            int i0 = grp + 8 * k;
            int e0 = s_i[wv][i0];
            float m0 = s_w[wv][i0];
            uint4 r0 = *(const uint4*)(He_bf + (size_t)e0 * DD + gl * 8);
            h[0] = fmaf(m0, bflo(r0.x), h[0]); h[1] = fmaf(m0, bfhi(r0.x), h[1]);
            h[2] = fmaf(m0, bflo(r0.y), h[2]); h[3] = fmaf(m0, bfhi(r0.y), h[3]);
            h[4] = fmaf(m0, bflo(r0.z), h[4]); h[5] = fmaf(m0, bfhi(r0.z), h[5]);
            h[6] = fmaf(m0, bflo(r0.w), h[6]); h[7] = fmaf(m0, bfhi(r0.w), h[7]);
        }
    }

    // wsum per-lane distinct: reduce 1,2,4 within groups first, then the
    // shared 8,16,32 rounds that also fold the per-group g/h partials.
    #pragma unroll
    for (int off = 1; off < 8; off <<= 1)
        wsum += __shfl_xor(wsum, off, 64);
    #pragma unroll
    for (int off = 8; off < 64; off <<= 1) {
        #pragma unroll
        for (int j = 0; j < 8; ++j) {
            g[j] += __shfl_xor(g[j], off, 64);
            h[j] += __shfl_xor(h[j], off, 64);
        }
        wsum += __shfl_xor(wsum, off, 64);
    }
    if (grp == 0) {
        float winv = (ge > gs) ? 1.0f / wsum : 0.f;
        float dvn = dvis[n];
        float o[8];
        #pragma unroll
        for (int j = 0; j < 8; ++j) {
            float x = 0.5f * (g[j] * winv + dvn * h[j]);
            o[j] = x > 0.f ? x : expm1f(x);
        }
        float* op = out + (size_t)n * DD + gl * 8;
        *(float4*)op       = make_float4(o[0], o[1], o[2], o[3]);
        *(float4*)(op + 4) = make_float4(o[4], o[5], o[6], o[7]);
    }
}

extern "C" void kernel_launch(void* const* d_in, const int* in_sizes, int n_in,
                              void* d_out, int out_size, void* d_ws, size_t ws_size,
                              hipStream_t stream)
{
    const float* X     = (const float*)d_in[0];
    const float* W     = (const float*)d_in[1];
    const float* bias  = (const float*)d_in[2];
    const float* a_src = (const float*)d_in[3];
    const float* a_dst = (const float*)d_in[4];
    const int* e_src   = (const int*)d_in[5];
    const int* e_dst   = (const int*)d_in[6];
    const int* inc_v   = (const int*)d_in[7];
    const int* inc_e   = (const int*)d_in[8];
    float* out = (float*)d_out;

    const int N = in_sizes[0] / DD;   // 50000
    const int E = in_sizes[5];        // 800000
    const int P = in_sizes[7];        // 200000
    const int M = 10000;
    const int Bg = (N + 511) >> 9, Bie = (M + 255) >> 8, Biv = Bg;

    char* p = (char*)d_ws;
    unsigned short* Xp_bf = (unsigned short*)p; p += (size_t)N * DD * 2;
    unsigned short* He_bf = (unsigned short*)p; p += (size_t)M * DD * 2;
    unsigned int* pg  = (unsigned int*)p; p += (size_t)E * 4;
    unsigned int* pie = (unsigned int*)p; p += (size_t)P * 4;
    unsigned int* piv = (unsigned int*)p; p += (size_t)P * 4;
    int* src_sorted = (int*)p; p += (size_t)E * 4;
    int* v_sorted   = (int*)p; p += (size_t)P * 4;
    int* e_sorted   = (int*)p; p += (size_t)P * 4;
    float* ssrc = (float*)p; p += (size_t)N * 4;
    float* sdst = (float*)p; p += (size_t)N * 4;
    float* dvis = (float*)p; p += (size_t)N * 4;
    float* dein = (float*)p; p += (size_t)M * 4;
    int* start_g = (int*)p; p += (size_t)(N + 1) * 4;
    int* start_v = (int*)p; p += (size_t)(N + 1) * 4;
    int* start_e = (int*)p; p += (size_t)(M + 1) * 4;
    int* hist_g  = (int*)p; p += (size_t)(Bg * 256 + 1) * 4;
    int* hist_ie = (int*)p; p += (size_t)(Bie * 128 + 1) * 4;
    int* hist_iv = (int*)p; p += (size_t)(Biv * 128 + 1) * 4;

    k_gemm_count<<<GEMM_BLOCKS + 512, 256, 0, stream>>>(
        X, W, bias, a_src, a_dst, Xp_bf, ssrc, sdst,
        e_dst, inc_e, inc_v, hist_g, hist_ie, hist_iv, N, E, P, M);
    k_scan3<<<3, 1024, 0, stream>>>(hist_g, Bg * 256, hist_ie, Bie * 128,
                                    hist_iv, Biv * 128);
    k_scat<<<512, 256, 0, stream>>>(e_dst, e_src, inc_e, inc_v,
                                    hist_g, hist_ie, hist_iv, pg, pie, piv,
                                    E, P, N, M);
    k_fine<<<Bg + Bie + Biv, 256, 0, stream>>>(hist_g, hist_ie, hist_iv, pg, pie, piv,
                                               src_sorted, v_sorted, e_sorted,
                                               start_g, start_e, start_v,
                                               dein, dvis, N, M);
    k_he<<<(M * DD + 255) / 256, 256, 0, stream>>>(start_e, v_sorted, Xp_bf, dvis,
                                                   dein, He_bf, M);
    k_out<<<(N * DD + 255) / 256, 256, 0, stream>>>(start_g, src_sorted, start_v,
                                                    e_sorted, ssrc, sdst, Xp_bf,
                                                    He_bf, dvis, out, N);
}

// Round 10
// 104.304 us; speedup vs baseline: 1.1304x; 1.1304x over previous
//
#include <hip/hip_runtime.h>
#include <math.h>

#define DD 64

typedef __attribute__((ext_vector_type(8))) short bf16x8;
typedef __attribute__((ext_vector_type(4))) float f32x4;

__device__ __forceinline__ unsigned short f2bf(float x) {
    unsigned int u = __float_as_uint(x);
    u += 0x7fffu + ((u >> 16) & 1u);      // round-to-nearest-even
    return (unsigned short)(u >> 16);
}
__device__ __forceinline__ float bflo(unsigned int u) { return __uint_as_float(u << 16); }
__device__ __forceinline__ float bfhi(unsigned int u) { return __uint_as_float(u & 0xffff0000u); }

// ---------------------------------------------------------------------------
// Fused: blocks [0,GB): MFMA GEMM (Xp_bf, s_src, s_dst).
//        blocks [GB, GB+512): multisplit coarse histograms.
// ---------------------------------------------------------------------------
#define GEMM_BLOCKS 196

__global__ __launch_bounds__(256) void k_gemm_count(
    const float* __restrict__ X, const float* __restrict__ W,
    const float* __restrict__ bias, const float* __restrict__ a_src,
    const float* __restrict__ a_dst, unsigned short* __restrict__ Xp_bf,
    float* __restrict__ s_src, float* __restrict__ s_dst,
    const int* __restrict__ e_dst, const int* __restrict__ inc_e,
    const int* __restrict__ inc_v, int* __restrict__ hist_g,
    int* __restrict__ hist_ie, int* __restrict__ hist_iv,
    int N, int E, int P, int M)
{
    if (blockIdx.x >= GEMM_BLOCKS) {
        // ---------------- histogram branch ----------------
        __shared__ int cnt[128];
        int b = blockIdx.x - GEMM_BLOCKS;
        const int* key; int n, B, SH, nblk, blk; int* hist;
        if (b < 256)      { key = e_dst; n = E; B = (N + 511) >> 9; SH = 9; nblk = 256; blk = b;       hist = hist_g;  }
        else if (b < 384) { key = inc_e; n = P; B = (M + 255) >> 8; SH = 8; nblk = 128; blk = b - 256; hist = hist_ie; }
        else              { key = inc_v; n = P; B = (N + 511) >> 9; SH = 9; nblk = 128; blk = b - 384; hist = hist_iv; }
        for (int i = threadIdx.x; i < B; i += 256) cnt[i] = 0;
        __syncthreads();
        int chunk = (n + nblk - 1) / nblk;
        int s = blk * chunk, e = min(n, s + chunk);
        for (int i = s + threadIdx.x; i < e; i += 256)
            atomicAdd(&cnt[key[i] >> SH], 1);
        __syncthreads();
        for (int i = threadIdx.x; i < B; i += 256)
            hist[i * nblk + blk] = cnt[i];
        return;
    }
    // ---------------- GEMM branch ----------------
    int t = threadIdx.x;
    int lane = t & 63;
    int col = lane & 15;
    int kq  = lane >> 4;
    int rowbase = kq * 4;

    bf16x8 bfrag[4][2];
    float bj[4], asr[4], adr[4];
    #pragma unroll
    for (int jt = 0; jt < 4; ++jt) {
        int j = jt * 16 + col;
        #pragma unroll
        for (int ks = 0; ks < 2; ++ks) {
            const float* wp = W + j * DD + ks * 32 + kq * 8;
            float4 w0 = *(const float4*)wp;
            float4 w1 = *(const float4*)(wp + 4);
            bf16x8 bb;
            bb[0] = (short)f2bf(w0.x); bb[1] = (short)f2bf(w0.y);
            bb[2] = (short)f2bf(w0.z); bb[3] = (short)f2bf(w0.w);
            bb[4] = (short)f2bf(w1.x); bb[5] = (short)f2bf(w1.y);
            bb[6] = (short)f2bf(w1.z); bb[7] = (short)f2bf(w1.w);
            bfrag[jt][ks] = bb;
        }
        bj[jt]  = bias[j];
        asr[jt] = a_src[j];
        adr[jt] = a_dst[j];
    }

    int wave  = (blockIdx.x * 256 + t) >> 6;
    int nwave = (GEMM_BLOCKS * 256) >> 6;
    int ntiles = (N + 15) >> 4;
    for (int tile = wave; tile < ntiles; tile += nwave) {
        int r0 = tile * 16;
        int rl = r0 + col;
        if (rl >= N) rl = N - 1;
        const float* xp = X + (size_t)rl * DD + kq * 8;
        float4 x0 = *(const float4*)xp;
        float4 x1 = *(const float4*)(xp + 4);
        float4 x2 = *(const float4*)(xp + 32);
        float4 x3 = *(const float4*)(xp + 36);
        bf16x8 a0, a1;
        a0[0] = (short)f2bf(x0.x); a0[1] = (short)f2bf(x0.y);
        a0[2] = (short)f2bf(x0.z); a0[3] = (short)f2bf(x0.w);
        a0[4] = (short)f2bf(x1.x); a0[5] = (short)f2bf(x1.y);
        a0[6] = (short)f2bf(x1.z); a0[7] = (short)f2bf(x1.w);
        a1[0] = (short)f2bf(x2.x); a1[1] = (short)f2bf(x2.y);
        a1[2] = (short)f2bf(x2.z); a1[3] = (short)f2bf(x2.w);
        a1[4] = (short)f2bf(x3.x); a1[5] = (short)f2bf(x3.y);
        a1[6] = (short)f2bf(x3.z); a1[7] = (short)f2bf(x3.w);

        f32x4 acc[4];
        #pragma unroll
        for (int jt = 0; jt < 4; ++jt) {
            f32x4 c = {bj[jt], bj[jt], bj[jt], bj[jt]};
            c = __builtin_amdgcn_mfma_f32_16x16x32_bf16(a0, bfrag[jt][0], c, 0, 0, 0);
            c = __builtin_amdgcn_mfma_f32_16x16x32_bf16(a1, bfrag[jt][1], c, 0, 0, 0);
            acc[jt] = c;
        }

        int orow = r0 + rowbase;
        #pragma unroll
        for (int jt = 0; jt < 4; ++jt) {
            #pragma unroll
            for (int r = 0; r < 4; ++r) {
                int rr = orow + r;
                if (rr < N)
                    Xp_bf[(size_t)rr * DD + jt * 16 + col] = f2bf(acc[jt][r]);
            }
        }

        float vs[4], vd[4];
        #pragma unroll
        for (int r = 0; r < 4; ++r) {
            vs[r] = acc[0][r] * asr[0] + acc[1][r] * asr[1]
                  + acc[2][r] * asr[2] + acc[3][r] * asr[3];
            vd[r] = acc[0][r] * adr[0] + acc[1][r] * adr[1]
                  + acc[2][r] * adr[2] + acc[3][r] * adr[3];
        }
        #pragma unroll
        for (int off = 1; off < 16; off <<= 1) {
            #pragma unroll
            for (int r = 0; r < 4; ++r) {
                vs[r] += __shfl_xor(vs[r], off, 64);
                vd[r] += __shfl_xor(vd[r], off, 64);
            }
        }
        if (col == 0) {
            #pragma unroll
            for (int r = 0; r < 4; ++r) {
                int rr = orow + r;
                if (rr < N) { s_src[rr] = vs[r]; s_dst[rr] = vd[r]; }
            }
        }
    }
}

// ---------------------------------------------------------------------------
// In-place exclusive scan (one block, 1024 threads, 4 elems/thread).
// ---------------------------------------------------------------------------
__device__ void block_scan4(int* a, int len)
{
    __shared__ int wtot[16];
    __shared__ int carry_s;
    int tid = threadIdx.x, lane = tid & 63, wid = tid >> 6;
    if (tid == 0) carry_s = 0;
    __syncthreads();
    for (int base = 0; base < len; base += 4096) {
        int i0 = base + tid * 4;
        int v[4];
        #pragma unroll
        for (int k = 0; k < 4; ++k) { int i = i0 + k; v[k] = (i < len) ? a[i] : 0; }
        int s = v[0] + v[1] + v[2] + v[3];
        int incl = s;
        #pragma unroll
        for (int off = 1; off < 64; off <<= 1) {
            int t = __shfl_up(incl, off, 64);
            if (lane >= off) incl += t;
        }
        if (lane == 63) wtot[wid] = incl;
        __syncthreads();
        int carry = carry_s;
        int woff = 0;
        for (int wj = 0; wj < wid; ++wj) woff += wtot[wj];
        int excl = carry + woff + incl - s;
        int run = excl;
        #pragma unroll
        for (int k = 0; k < 4; ++k) { int i = i0 + k; if (i < len) a[i] = run; run += v[k]; }
        __syncthreads();
        if (tid == 1023) carry_s = run;
        __syncthreads();
    }
    if (tid == 0) a[len] = carry_s;
}

__global__ __launch_bounds__(1024) void k_scan3(
    int* h0, int l0, int* h1, int l1, int* h2, int l2)
{
    if (blockIdx.x == 0)      block_scan4(h0, l0);
    else if (blockIdx.x == 1) block_scan4(h1, l1);
    else                      block_scan4(h2, l2);
}

// ---------------------------------------------------------------------------
// Multisplit pass 2: scatter PACKED (fine_key | payload<<SH) into
// per-(block,bucket) regions. 4 B per item.
// ---------------------------------------------------------------------------
__global__ __launch_bounds__(256) void k_scat(
    const int* __restrict__ e_dst, const int* __restrict__ e_src,
    const int* __restrict__ inc_e, const int* __restrict__ inc_v,
    const int* __restrict__ hist_g, const int* __restrict__ hist_ie,
    const int* __restrict__ hist_iv,
    unsigned int* __restrict__ pg, unsigned int* __restrict__ pie,
    unsigned int* __restrict__ piv,
    int E, int P, int N, int M)
{
    __shared__ int cur[128];
    int b = blockIdx.x;
    const int *key, *pay, *base; unsigned int* out;
    int n, B, SH, nblk, blk;
    if (b < 256)      { key = e_dst; pay = e_src; n = E; B = (N + 511) >> 9; SH = 9; nblk = 256; blk = b;       base = hist_g;  out = pg;  }
    else if (b < 384) { key = inc_e; pay = inc_v; n = P; B = (M + 255) >> 8; SH = 8; nblk = 128; blk = b - 256; base = hist_ie; out = pie; }
    else              { key = inc_v; pay = inc_e; n = P; B = (N + 511) >> 9; SH = 9; nblk = 128; blk = b - 384; base = hist_iv; out = piv; }
    for (int i = threadIdx.x; i < B; i += 256) cur[i] = base[i * nblk + blk];
    __syncthreads();
    int chunk = (n + nblk - 1) / nblk;
    int s = blk * chunk, e = min(n, s + chunk);
    int mask = (1 << SH) - 1;
    for (int i = s + threadIdx.x; i < e; i += 256) {
        int k = key[i];
        int pos = atomicAdd(&cur[k >> SH], 1);
        out[pos] = (unsigned int)(k & mask) | ((unsigned int)pay[i] << SH);
    }
}

// ---------------------------------------------------------------------------
// Multisplit pass 3: per-bucket fine counting sort in LDS (packed input).
// ---------------------------------------------------------------------------
__global__ __launch_bounds__(256) void k_fine(
    const int* __restrict__ hist_g, const int* __restrict__ hist_ie,
    const int* __restrict__ hist_iv,
    const unsigned int* __restrict__ pg, const unsigned int* __restrict__ pie,
    const unsigned int* __restrict__ piv,
    int* __restrict__ src_sorted, int* __restrict__ v_sorted,
    int* __restrict__ e_sorted,
    int* __restrict__ start_g, int* __restrict__ start_e,
    int* __restrict__ start_v,
    float* __restrict__ dein, float* __restrict__ dvis, int N, int M)
{
    __shared__ int lh[513];
    __shared__ int lc[512];
    __shared__ int lwt[4];
    __shared__ int lout[10240];
    int Bg = (N + 511) >> 9, Bie = (M + 255) >> 8;
    int b = blockIdx.x, tid = threadIdx.x;
    const int* base; const unsigned int* pr; int* outp; int* startp; float* inv;
    int K, nblk, b0, NK, mode;
    if (b < Bg)            { base = hist_g;  pr = pg;  outp = src_sorted; startp = start_g; inv = nullptr; K = 512; nblk = 256; b0 = b;            NK = N; mode = 0; }
    else if (b < Bg + Bie) { base = hist_ie; pr = pie; outp = v_sorted;   startp = start_e; inv = dein;    K = 256; nblk = 128; b0 = b - Bg;       NK = M; mode = 2; }
    else                   { base = hist_iv; pr = piv; outp = e_sorted;   startp = start_v; inv = dvis;    K = 512; nblk = 128; b0 = b - Bg - Bie; NK = N; mode = 1; }
    int SHF = (K == 512) ? 9 : 8;

    int pbase = base[b0 * nblk], pend = base[(b0 + 1) * nblk];
    int cnt = pend - pbase;
    for (int i = tid; i < K; i += 256) { lh[i] = 0; lc[i] = 0; }
    __syncthreads();
    for (int i = tid; i < cnt; i += 256)
        atomicAdd(&lh[pr[pbase + i] & (K - 1)], 1);
    __syncthreads();

    int per = K >> 8;
    int i0 = tid * per;
    int a0 = lh[i0], a1 = (per == 2) ? lh[i0 + 1] : 0;
    int ssum = a0 + a1;
    int lane = tid & 63, wid = tid >> 6;
    int incl = ssum;
    #pragma unroll
    for (int off = 1; off < 64; off <<= 1) {
        int t = __shfl_up(incl, off, 64);
        if (lane >= off) incl += t;
    }
    if (lane == 63) lwt[wid] = incl;
    __syncthreads();
    int woff = 0;
    for (int wj = 0; wj < wid; ++wj) woff += lwt[wj];
    int excl = woff + incl - ssum;
    lh[i0] = excl;
    if (per == 2) lh[i0 + 1] = excl + a0;
    if (tid == 255) lh[K] = excl + ssum;
    __syncthreads();

    for (int i = tid; i < cnt; i += 256) {
        unsigned int q = pr[pbase + i];
        int kl = q & (K - 1);
        int pos = lh[kl] + atomicAdd(&lc[kl], 1);
        lout[pos < 10240 ? pos : 10239] = (int)(q >> SHF);
    }
    __syncthreads();
    for (int i = tid; i < cnt; i += 256)
        outp[pbase + i] = lout[i];
    for (int k = tid; k < K; k += 256) {
        int node = b0 * K + k;
        if (node < NK) {
            startp[node] = pbase + lh[k];
            if (mode) {
                int d = lh[k + 1] - lh[k];
                inv[node] = d > 0 ? (mode == 1 ? rsqrtf((float)d) : 1.0f / (float)d) : 0.0f;
            }
        }
    }
    int Bj = (NK + K - 1) / K;
    if (tid == 0 && b0 == Bj - 1) startp[NK] = pend;
}

// ---------------------------------------------------------------------------
// He_bf[e][:] = bf16( dein[e] * sum_v Xp[v][:]*dvis[v] ).
// Wave per hyperedge, HALF-WAVE layout: lane (hl = lane&31) owns dword hl of
// the row (dims 2hl, 2hl+1); the two 32-lane halves process different
// members. Per load instr the wave reads 2 full rows coalesced. Epilogue
// reduce = one shfl_xor(32) for a0/a1.
// ---------------------------------------------------------------------------
__global__ __launch_bounds__(256, 8) void k_he(
    const int* __restrict__ start_e, const int* __restrict__ v_sorted,
    const unsigned short* __restrict__ Xp_bf, const float* __restrict__ dvis,
    const float* __restrict__ dein, unsigned short* __restrict__ He_bf, int M)
{
    __shared__ int   s_v[4][64];
    __shared__ float s_d[4][64];
    int lane = threadIdx.x & 63, half = lane >> 5, hl = lane & 31;
    int wv = threadIdx.x >> 6;
    int e = (blockIdx.x * 256 + threadIdx.x) >> 6;
    if (e >= M) return;
    int s = start_e[e], t = start_e[e + 1];
    float a0 = 0.f, a1 = 0.f;
    for (int base = s; base < t; base += 64) {
        int cnt = min(64, t - base);          // wave-uniform
        int v = 0; float dv = 0.f;
        if (lane < cnt) { v = v_sorted[base + lane]; dv = dvis[v]; }
        s_v[wv][lane] = v;
        s_d[wv][lane] = dv;
        int nPair = (cnt + 1) >> 1;           // wave-uniform
        int k = 0;
        for (; k + 1 < nPair; k += 2) {
            int i0 = 2 * k + half, i1 = i0 + 2;
            int v0 = s_v[wv][i0]; float d0 = s_d[wv][i0];
            int v1 = s_v[wv][i1]; float d1 = s_d[wv][i1];
            unsigned r0 = *(const unsigned*)(Xp_bf + (size_t)v0 * DD + hl * 2);
            unsigned r1 = *(const unsigned*)(Xp_bf + (size_t)v1 * DD + hl * 2);
            a0 = fmaf(d0, bflo(r0), a0); a1 = fmaf(d0, bfhi(r0), a1);
            a0 = fmaf(d1, bflo(r1), a0); a1 = fmaf(d1, bfhi(r1), a1);
        }
        if (k < nPair) {                      // wave-uniform tail
            int i0 = 2 * k + half;
            int v0 = s_v[wv][i0]; float d0 = s_d[wv][i0];
            unsigned r0 = *(const unsigned*)(Xp_bf + (size_t)v0 * DD + hl * 2);
            a0 = fmaf(d0, bflo(r0), a0); a1 = fmaf(d0, bfhi(r0), a1);
        }
    }
    a0 += __shfl_xor(a0, 32, 64);
    a1 += __shfl_xor(a1, 32, 64);
    if (half == 0) {
        float din = dein[e];
        unsigned o = (unsigned)f2bf(a0 * din) | ((unsigned)f2bf(a1 * din) << 16);
        *(unsigned*)(He_bf + (size_t)e * DD + hl * 2) = o;
    }
}

// ---------------------------------------------------------------------------
// Per-node fused epilogue, HALF-WAVE layout. Adjacency batch staged into
// per-wave LDS (coalesced index load, lane-parallel exp); each half-wave
// processes one edge per step, lane owns one dword of the row. Accumulators:
// g0,g1,h0,h1,wsum. Epilogue: 1 shfl_xor(32) round + wsum reduce; coalesced
// float2 store.
// ---------------------------------------------------------------------------
__global__ __launch_bounds__(256, 8) void k_out(
    const int* __restrict__ start_g, const int* __restrict__ src_sorted,
    const int* __restrict__ start_v, const int* __restrict__ e_sorted,
    const float* __restrict__ ssrc, const float* __restrict__ sdst,
    const unsigned short* __restrict__ Xp_bf, const unsigned short* __restrict__ He_bf,
    const float* __restrict__ dvis, float* __restrict__ out, int N)
{
    __shared__ int   s_i[4][64];
    __shared__ float s_w[4][64];
    int lane = threadIdx.x & 63, half = lane >> 5, hl = lane & 31;
    int wv = threadIdx.x >> 6;
    int n = (blockIdx.x * 256 + threadIdx.x) >> 6;
    if (n >= N) return;

    float sd = sdst[n];
    int gs = start_g[n], ge = start_g[n + 1];
    float g0 = 0.f, g1 = 0.f, wsum = 0.f;
    for (int base = gs; base < ge; base += 64) {
        int cnt = min(64, ge - base);         // wave-uniform
        int idx = 0; float w = 0.f;
        if (lane < cnt) {
            idx = src_sorted[base + lane];
            float sc = ssrc[idx] + sd;
            sc = sc > 0.f ? sc : 0.2f * sc;
            w = __expf(sc);
        }
        s_i[wv][lane] = idx;
        s_w[wv][lane] = w;
        wsum += w;
        int nPair = (cnt + 1) >> 1;           // wave-uniform
        int k = 0;
        for (; k + 1 < nPair; k += 2) {
            int i0 = 2 * k + half, i1 = i0 + 2;
            int s0 = s_i[wv][i0]; float w0 = s_w[wv][i0];
            int s1 = s_i[wv][i1]; float w1 = s_w[wv][i1];
            unsigned r0 = *(const unsigned*)(Xp_bf + (size_t)s0 * DD + hl * 2);
            unsigned r1 = *(const unsigned*)(Xp_bf + (size_t)s1 * DD + hl * 2);
            g0 = fmaf(w0, bflo(r0), g0); g1 = fmaf(w0, bfhi(r0), g1);
            g0 = fmaf(w1, bflo(r1), g0); g1 = fmaf(w1, bfhi(r1), g1);
        }
        if (k < nPair) {                      // wave-uniform tail
            int i0 = 2 * k + half;
            int s0 = s_i[wv][i0]; float w0 = s_w[wv][i0];
            unsigned r0 = *(const unsigned*)(Xp_bf + (size_t)s0 * DD + hl * 2);
            g0 = fmaf(w0, bflo(r0), g0); g1 = fmaf(w0, bfhi(r0), g1);
        }
    }

    int vs = start_v[n], ve = start_v[n + 1];
    float h0 = 0.f, h1 = 0.f;
    for (int base = vs; base < ve; base += 64) {
        int cnt = min(64, ve - base);         // wave-uniform
        int eidx = 0; float hw = 0.f;
        if (lane < cnt) { eidx = e_sorted[base + lane]; hw = 1.f; }
        s_i[wv][lane] = eidx;
        s_w[wv][lane] = hw;
        int nPair = (cnt + 1) >> 1;           // wave-uniform
        int k = 0;
        for (; k + 1 < nPair; k += 2) {
            int i0 = 2 * k + half, i1 = i0 + 2;
            int e0 = s_i[wv][i0]; float m0 = s_w[wv][i0];
            int e1 = s_i[wv][i1]; float m1 = s_w[wv][i1];
            unsigned r0 = *(const unsigned*)(He_bf + (size_t)e0 * DD + hl * 2);
            unsigned r1 = *(const unsigned*)(He_bf + (size_t)e1 * DD + hl * 2);
            h0 = fmaf(m0, bflo(r0), h0); h1 = fmaf(m0, bfhi(r0), h1);
            h0 = fmaf(m1, bflo(r1), h0); h1 = fmaf(m1, bfhi(r1), h1);
        }
        if (k < nPair) {                      // wave-uniform tail
            int i0 = 2 * k + half;
            int e0 = s_i[wv][i0]; float m0 = s_w[wv][i0];
            unsigned r0 = *(const unsigned*)(He_bf + (size_t)e0 * DD + hl * 2);
            h0 = fmaf(m0, bflo(r0), h0); h1 = fmaf(m0, bfhi(r0), h1);
        }
    }

    // wsum: full 64-lane reduce (computed lane-parallel). g/h: cross-half.
    #pragma unroll
    for (int off = 1; off < 64; off <<= 1)
        wsum += __shfl_xor(wsum, off, 64);
    g0 += __shfl_xor(g0, 32, 64);
    g1 += __shfl_xor(g1, 32, 64);
    h0 += __shfl_xor(h0, 32, 64);
    h1 += __shfl_xor(h1, 32, 64);

    if (half == 0) {
        float winv = (ge > gs) ? 1.0f / wsum : 0.f;
        float dvn = dvis[n];
        float x0 = 0.5f * (g0 * winv + dvn * h0);
        float x1 = 0.5f * (g1 * winv + dvn * h1);
        x0 = x0 > 0.f ? x0 : expm1f(x0);
        x1 = x1 > 0.f ? x1 : expm1f(x1);
        *(float2*)(out + (size_t)n * DD + hl * 2) = make_float2(x0, x1);
    }
}

extern "C" void kernel_launch(void* const* d_in, const int* in_sizes, int n_in,
                              void* d_out, int out_size, void* d_ws, size_t ws_size,
                              hipStream_t stream)
{
    const float* X     = (const float*)d_in[0];
    const float* W     = (const float*)d_in[1];
    const float* bias  = (const float*)d_in[2];
    const float* a_src = (const float*)d_in[3];
    const float* a_dst = (const float*)d_in[4];
    const int* e_src   = (const int*)d_in[5];
    const int* e_dst   = (const int*)d_in[6];
    const int* inc_v   = (const int*)d_in[7];
    const int* inc_e   = (const int*)d_in[8];
    float* out = (float*)d_out;

    const int N = in_sizes[0] / DD;   // 50000
    const int E = in_sizes[5];        // 800000
    const int P = in_sizes[7];        // 200000
    const int M = 10000;
    const int Bg = (N + 511) >> 9, Bie = (M + 255) >> 8, Biv = Bg;

    char* p = (char*)d_ws;
    unsigned short* Xp_bf = (unsigned short*)p; p += (size_t)N * DD * 2;
    unsigned short* He_bf = (unsigned short*)p; p += (size_t)M * DD * 2;
    unsigned int* pg  = (unsigned int*)p; p += (size_t)E * 4;
    unsigned int* pie = (unsigned int*)p; p += (size_t)P * 4;
    unsigned int* piv = (unsigned int*)p; p += (size_t)P * 4;
    int* src_sorted = (int*)p; p += (size_t)E * 4;
    int* v_sorted   = (int*)p; p += (size_t)P * 4;
    int* e_sorted   = (int*)p; p += (size_t)P * 4;
    float* ssrc = (float*)p; p += (size_t)N * 4;
    float* sdst = (float*)p; p += (size_t)N * 4;
    float* dvis = (float*)p; p += (size_t)N * 4;
    float* dein = (float*)p; p += (size_t)M * 4;
    int* start_g = (int*)p; p += (size_t)(N + 1) * 4;
    int* start_v = (int*)p; p += (size_t)(N + 1) * 4;
    int* start_e = (int*)p; p += (size_t)(M + 1) * 4;
    int* hist_g  = (int*)p; p += (size_t)(Bg * 256 + 1) * 4;
    int* hist_ie = (int*)p; p += (size_t)(Bie * 128 + 1) * 4;
    int* hist_iv = (int*)p; p += (size_t)(Biv * 128 + 1) * 4;

    k_gemm_count<<<GEMM_BLOCKS + 512, 256, 0, stream>>>(
        X, W, bias, a_src, a_dst, Xp_bf, ssrc, sdst,
        e_dst, inc_e, inc_v, hist_g, hist_ie, hist_iv, N, E, P, M);
    k_scan3<<<3, 1024, 0, stream>>>(hist_g, Bg * 256, hist_ie, Bie * 128,
                                    hist_iv, Biv * 128);
    k_scat<<<512, 256, 0, stream>>>(e_dst, e_src, inc_e, inc_v,
                                    hist_g, hist_ie, hist_iv, pg, pie, piv,
                                    E, P, N, M);
    k_fine<<<Bg + Bie + Biv, 256, 0, stream>>>(hist_g, hist_ie, hist_iv, pg, pie, piv,
                                               src_sorted, v_sorted, e_sorted,
                                               start_g, start_e, start_v,
                                               dein, dvis, N, M);
    k_he<<<(M * DD + 255) / 256, 256, 0, stream>>>(start_e, v_sorted, Xp_bf, dvis,
                                                   dein, He_bf, M);
    k_out<<<(N * DD + 255) / 256, 256, 0, stream>>>(start_g, src_sorted, start_v,
                                                    e_sorted, ssrc, sdst, Xp_bf,
                                                    He_bf, dvis, out, N);
}